// Round 1
// baseline (460.873 us; speedup 1.0000x reference)
//
#include <hip/hip_runtime.h>

// GAP-TV CASSI reconstruction, H=W=512, L=28, 12 iterations, sigma=0.5 Gaussian.
// Dispersion offsets resolve to dx[l]=l, dy[l]=0  (rint of s*cos(1deg), s*sin(1deg)).
#define HH 512
#define WW 512
#define LL 28
#define WP 539              // W + dx_max (27)
#define NPIX (HH * WP)      // 512*539 = 275968
#define NX (LL * HH * WW)   // 28*512*512

// ---------------- setup: phi_inv = 1/max(sum_l mask_shift, 1);  y1 = y ----------------
__global__ void k_setup(const float* __restrict__ y, const float* __restrict__ mask,
                        float* __restrict__ phi_inv, float* __restrict__ y1) {
    int idx = blockIdx.x * blockDim.x + threadIdx.x;
    if (idx >= NPIX) return;
    int i = idx / WP, jp = idx - i * WP;
    int lmin = jp - (WW - 1); if (lmin < 0) lmin = 0;
    int lmax = jp < (LL - 1) ? jp : (LL - 1);
    float s = 0.f;
    for (int l = lmin; l <= lmax; ++l) s += mask[i * WW + (jp - l)];
    phi_inv[idx] = 1.0f / fmaxf(s, 1.0f);
    y1[idx] = y[idx];
}

// ---------------- x = At(y): x[l,i,j] = y[i,j+l] * mask[i,j] ----------------
__global__ void k_xinit(const float* __restrict__ y, const float* __restrict__ mask,
                        float* __restrict__ x) {
    int idx = blockIdx.x * blockDim.x + threadIdx.x;
    if (idx >= NX) return;
    int l = idx / (HH * WW);
    int r = idx - l * HH * WW;
    int i = r / WW, j = r - i * WW;
    x[idx] = y[i * WP + j + l] * mask[i * WW + j];
}

// ---------------- per-iteration step 1: yb = A(x); y1 += y - yb; t = (y1 - yb)*phi_inv ----------------
__global__ void k_fwd(const float* __restrict__ x, const float* __restrict__ mask,
                      const float* __restrict__ y, const float* __restrict__ phi_inv,
                      float* __restrict__ y1, float* __restrict__ t) {
    int idx = blockIdx.x * blockDim.x + threadIdx.x;
    if (idx >= NPIX) return;
    int i = idx / WP, jp = idx - i * WP;
    int lmin = jp - (WW - 1); if (lmin < 0) lmin = 0;
    int lmax = jp < (LL - 1) ? jp : (LL - 1);
    float yb = 0.f;
    const float* mrow = mask + i * WW;
    for (int l = lmin; l <= lmax; ++l) {
        int j = jp - l;
        yb = fmaf(mrow[j], x[(size_t)l * HH * WW + i * WW + j], yb);
    }
    float y1n = y1[idx] + y[idx] - yb;
    y1[idx] = y1n;
    t[idx] = (y1n - yb) * phi_inv[idx];
}

// ---------------- per-iteration step 2 (fused): xo = blur5x5( x + At(t) ) ----------------
#define TX 64
#define TY 16
__global__ void k_upblur(const float* __restrict__ x, const float* __restrict__ t,
                         const float* __restrict__ mask, float* __restrict__ xo,
                         float w0, float w1, float w2) {
    __shared__ float u[(TY + 4)][(TX + 4)];
    __shared__ float hb[(TY + 4)][TX];
    const int l  = blockIdx.z;
    const int bi = blockIdx.y * TY;
    const int bj = blockIdx.x * TX;
    const int tid = threadIdx.x;   // blockDim.x == 256
    const float* xl = x + (size_t)l * HH * WW;

    // stage u = x + At(t) with 2-halo, zero outside [0,H)x[0,W)
    for (int idx = tid; idx < (TY + 4) * (TX + 4); idx += 256) {
        int r = idx / (TX + 4), c = idx - r * (TX + 4);
        int gi = bi + r - 2, gj = bj + c - 2;
        float v = 0.f;
        if (gi >= 0 && gi < HH && gj >= 0 && gj < WW) {
            v = xl[gi * WW + gj] + t[gi * WP + gj + l] * mask[gi * WW + gj];
        }
        u[r][c] = v;
    }
    __syncthreads();

    // horizontal blur into hb (all TY+4 rows)
    for (int idx = tid; idx < (TY + 4) * TX; idx += 256) {
        int r = idx / TX, c = idx - r * TX;
        hb[r][c] = w2 * (u[r][c] + u[r][c + 4])
                 + w1 * (u[r][c + 1] + u[r][c + 3])
                 + w0 * u[r][c + 2];
    }
    __syncthreads();

    // vertical blur, write output
    for (int idx = tid; idx < TY * TX; idx += 256) {
        int r = idx / TX, c = idx - r * TX;
        float o = w2 * (hb[r][c] + hb[r + 4][c])
                + w1 * (hb[r + 1][c] + hb[r + 3][c])
                + w0 * hb[r + 2][c];
        xo[((size_t)l * HH + bi + r) * WW + bj + c] = o;
    }
}

extern "C" void kernel_launch(void* const* d_in, const int* in_sizes, int n_in,
                              void* d_out, int out_size, void* d_ws, size_t ws_size,
                              hipStream_t stream) {
    const float* y    = (const float*)d_in[0];   // [1, 512, 539]
    const float* mask = (const float*)d_in[1];   // [512, 512]
    // d_in[2] (phi_d_deg) and d_in[3] (s_nom) only determine the compile-time offsets.

    float* out = (float*)d_out;                  // [1, 28, 512, 512] -> also x ping-pong buffer B

    float* phi_inv = (float*)d_ws;               // NPIX
    float* y1      = phi_inv + NPIX;             // NPIX
    float* t       = y1 + NPIX;                  // NPIX
    float* xA      = t + NPIX;                   // NX  (ping-pong buffer A)
    float* xB      = out;

    // Gaussian weights (sigma = 0.5, ksize = 5): g = exp(-2*k^2), normalized.
    float g1 = expf(-2.0f), g2 = expf(-8.0f);
    float gs = 1.0f + 2.0f * g1 + 2.0f * g2;
    float w0 = 1.0f / gs, w1 = g1 / gs, w2 = g2 / gs;

    const int BT = 256;
    const int gpix = (NPIX + BT - 1) / BT;

    k_setup<<<gpix, BT, 0, stream>>>(y, mask, phi_inv, y1);
    k_xinit<<<(NX + BT - 1) / BT, BT, 0, stream>>>(y, mask, xB);

    float* cur = xB;
    float* nxt = xA;
    for (int it = 0; it < 12; ++it) {
        k_fwd<<<gpix, BT, 0, stream>>>(cur, mask, y, phi_inv, y1, t);
        k_upblur<<<dim3(WW / TX, HH / TY, LL), BT, 0, stream>>>(cur, t, mask, nxt, w0, w1, w2);
        float* tmp = cur; cur = nxt; nxt = tmp;
    }
    // 12 iterations = even number of swaps: final write landed in xB == d_out.
}